// Round 9
// baseline (299.758 us; speedup 1.0000x reference)
//
#include <hip/hip_runtime.h>
#include <math.h>

#define LN_EPS 1e-5f

typedef _Float16 half_t;
typedef _Float16 half8_t __attribute__((ext_vector_type(8)));
typedef _Float16 half4_t __attribute__((ext_vector_type(4)));
typedef _Float16 half2_t __attribute__((ext_vector_type(2)));
typedef float f32x4 __attribute__((ext_vector_type(4)));

// ===========================================================================
// Weight-prep: reorder conv weights into MFMA B-fragment order (fp16).
// ===========================================================================
__global__ void prep_weights_kernel(const float* __restrict__ w2,
                                    const float* __restrict__ w3,
                                    const float* __restrict__ w4,
                                    half_t* __restrict__ F2,
                                    half_t* __restrict__ F3,
                                    half_t* __restrict__ F4)
{
    const int bid = blockIdx.x;
    const int t   = threadIdx.x;
    const int flat0 = t * 2;
    const int l  = flat0 >> 3;
    const int j0 = flat0 & 7;

    int layer, sn;
    half_t* dst;
    if (bid < 16)      { layer = 2; sn = bid;      dst = F2; }
    else if (bid < 40) { layer = 3; sn = bid - 16; dst = F3; }
    else               { layer = 4; sn = bid - 40; dst = F4; }
    const int s  = sn >> 1;
    const int nt = sn & 1;
    const int oc = nt * 16 + (l & 15);

    float v[2];
    #pragma unroll
    for (int u = 0; u < 2; ++u) {
        const int j = j0 + u;
        const int k = s * 32 + ((l >> 4) * 8) + j;
        float val = 0.f;
        if (layer == 2) {
            const int ky = k >> 6, rem = k & 63, kx = rem >> 4, ic = rem & 15;
            if (oc < 20) val = w2[(oc * 16 + ic) * 16 + ky * 4 + kx];
        } else if (layer == 3) {
            const int ky = k / 96, rem = k % 96, kx = rem / 24, ic = rem % 24;
            if (oc < 24 && ic < 20) val = w3[(oc * 20 + ic) * 16 + ky * 4 + kx];
        } else {
            const int ky = k / 96, rem = k % 96, kx = rem / 24, ic = rem % 24;
            if (oc < 30) val = w4[(oc * 24 + ic) * 16 + ky * 4 + kx];
        }
        v[u] = val;
    }
    half2_t outv;
    outv[0] = (half_t)v[0];
    outv[1] = (half_t)v[1];
    *(half2_t*)&dst[(sn * 64 + l) * 8 + j0] = outv;
}

// ===========================================================================
// Fused conv stack, MFMA implicit GEMM (unchanged — passing, ~100us).
// ===========================================================================
__global__ __launch_bounds__(256, 2) void conv_fused_kernel(
    const float* __restrict__ x,
    const float* __restrict__ w1, const float* __restrict__ b1,
    const float* __restrict__ b2, const float* __restrict__ b3,
    const float* __restrict__ b4,
    const half_t* __restrict__ F2, const half_t* __restrict__ F3,
    const half_t* __restrict__ F4,
    half_t* __restrict__ hout)
{
    __shared__ __attribute__((aligned(16))) char LBUF[45280];
    float*  xw = (float*)LBUF;
    char*   plane2b = LBUF;                 // conv2 out / conv4 stage region
    char*   plane1b = LBUF + 23232;         // conv1 out / conv3 out region
    half_t* plane2h = (half_t*)plane2b;
    half_t* plane1h = (half_t*)plane1b;
    half_t* plane3h = (half_t*)plane1b;
    half_t* stage   = (half_t*)plane2b;     // conv4 staging [256][32] fp16

    const int b    = blockIdx.x;
    const int tid  = threadIdx.x;
    const int wave = tid >> 6;
    const int l    = tid & 63;
    const int col  = l & 15;
    const int g    = l >> 4;

    {
        const float4* gx = (const float4*)(x + (size_t)b * 784);
        if (tid < 196) ((float4*)xw)[tid] = gx[tid];
        const int i = tid;
        if (i < 256) xw[784 + (i & 15) * 16 + (i >> 4)] = w1[i];
        if (tid < 16) xw[1040 + tid] = b1[tid];
    }
    __syncthreads();

    // ---- conv1 (fp32 VALU): 1->16, 28x28 -> 25x25, HWC fp16 out ----
    {
        const float* xs  = xw;
        const float* w1s = xw + 784;
        const float* b1s = xw + 1040;
        const int p0 = tid, p1 = tid + 256;
        const bool v2 = (tid + 512) < 625;
        const int p2 = v2 ? tid + 512 : 624;
        const int y0 = p0 / 25, x0 = p0 % 25;
        const int y1 = p1 / 25, x1 = p1 % 25;
        const int y2 = p2 / 25, x2 = p2 % 25;
        float a0[16], a1[16], a2[16];
        #pragma unroll
        for (int oc = 0; oc < 16; ++oc) { const float bb = b1s[oc]; a0[oc] = bb; a1[oc] = bb; a2[oc] = bb; }
        #pragma unroll
        for (int k = 0; k < 16; ++k) {
            const int ky = k >> 2, kx = k & 3;
            const float i0 = xs[(y0 + ky) * 28 + x0 + kx];
            const float i1 = xs[(y1 + ky) * 28 + x1 + kx];
            const float i2 = xs[(y2 + ky) * 28 + x2 + kx];
            #pragma unroll
            for (int oc4 = 0; oc4 < 4; ++oc4) {
                const float4 wv = *(const float4*)&w1s[k * 16 + oc4 * 4];
                const float wq[4] = {wv.x, wv.y, wv.z, wv.w};
                #pragma unroll
                for (int q = 0; q < 4; ++q) {
                    const int oc = oc4 * 4 + q;
                    a0[oc] += i0 * wq[q]; a1[oc] += i1 * wq[q]; a2[oc] += i2 * wq[q];
                }
            }
        }
        __syncthreads();   // xw reads done before plane1 writes overlap region? (disjoint, but cheap safety for x region reuse ordering)
        #pragma unroll
        for (int i2_ = 0; i2_ < 8; ++i2_) {
            half2_t h0, h1;
            h0[0] = (half_t)fmaxf(a0[2 * i2_], 0.f); h0[1] = (half_t)fmaxf(a0[2 * i2_ + 1], 0.f);
            h1[0] = (half_t)fmaxf(a1[2 * i2_], 0.f); h1[1] = (half_t)fmaxf(a1[2 * i2_ + 1], 0.f);
            *(half2_t*)&plane1h[p0 * 16 + 2 * i2_] = h0;
            *(half2_t*)&plane1h[p1 * 16 + 2 * i2_] = h1;
        }
        if (v2) {
            #pragma unroll
            for (int i2_ = 0; i2_ < 8; ++i2_) {
                half2_t h2v;
                h2v[0] = (half_t)fmaxf(a2[2 * i2_], 0.f); h2v[1] = (half_t)fmaxf(a2[2 * i2_ + 1], 0.f);
                *(half2_t*)&plane1h[p2 * 16 + 2 * i2_] = h2v;
            }
        }
    }
    __syncthreads();

    // ---- conv2 (MFMA): 16->20(pad24), 25x25 -> 22x22, K=256 (8 steps) ----
    {
        half8_t B2f[8][2];                       // loaded HERE (stage-local)
        const half8_t* Fv = (const half8_t*)F2;
        #pragma unroll
        for (int s = 0; s < 8; ++s) {
            B2f[s][0] = Fv[(s * 2 + 0) * 64 + l];
            B2f[s][1] = Fv[(s * 2 + 1) * 64 + l];
        }
        const float bias0 = b2[col];
        const float bias1 = (16 + col < 20) ? b2[16 + col] : 0.f;
        #pragma unroll 1
        for (int mt = wave; mt < 31; mt += 4) {
            const int pos = mt * 16 + col;
            const int py = pos / 22, px = pos - py * 22;
            const char* Ab = plane1b + (py * 25 + px) * 32 + g * 16;
            f32x4 c0 = {0.f, 0.f, 0.f, 0.f}, c1 = {0.f, 0.f, 0.f, 0.f};
            #pragma unroll
            for (int s = 0; s < 8; ++s) {
                const half8_t a = *(const half8_t*)(Ab + (s >> 1) * 800 + (s & 1) * 64);
                c0 = __builtin_amdgcn_mfma_f32_16x16x32_f16(a, B2f[s][0], c0, 0, 0, 0);
                c1 = __builtin_amdgcn_mfma_f32_16x16x32_f16(a, B2f[s][1], c1, 0, 0, 0);
            }
            #pragma unroll
            for (int r = 0; r < 4; ++r) {
                const int prow = mt * 16 + g * 4 + r;
                if (prow < 484) {
                    plane2h[prow * 24 + col] = (half_t)fmaxf(c0[r] + bias0, 0.f);
                    if (col < 8) {
                        const float v = (col < 4) ? fmaxf(c1[r] + bias1, 0.f) : 0.f;
                        plane2h[prow * 24 + 16 + col] = (half_t)v;
                    }
                }
            }
        }
    }
    __syncthreads();

    // ---- conv3 (MFMA): 24(in,pad)->24, 22x22 -> 19x19, K=384 (12 steps) ----
    {
        half8_t B3f[12][2];                      // loaded HERE
        const half8_t* Fv = (const half8_t*)F3;
        #pragma unroll
        for (int s = 0; s < 12; ++s) {
            B3f[s][0] = Fv[(s * 2 + 0) * 64 + l];
            B3f[s][1] = Fv[(s * 2 + 1) * 64 + l];
        }
        const float bias0 = b3[col];
        const float bias1 = b3[16 + (col & 7)];
        #pragma unroll 1
        for (int mt = wave; mt < 23; mt += 4) {
            const int pos = mt * 16 + col;
            const int py = pos / 19, px = pos - py * 19;
            const char* Ab = plane2b + (py * 22 + px) * 48 + g * 16;
            f32x4 c0 = {0.f, 0.f, 0.f, 0.f}, c1 = {0.f, 0.f, 0.f, 0.f};
            #pragma unroll
            for (int s = 0; s < 12; ++s) {
                const half8_t a = *(const half8_t*)(Ab + (s / 3) * 1056 + (s % 3) * 64);
                c0 = __builtin_amdgcn_mfma_f32_16x16x32_f16(a, B3f[s][0], c0, 0, 0, 0);
                c1 = __builtin_amdgcn_mfma_f32_16x16x32_f16(a, B3f[s][1], c1, 0, 0, 0);
            }
            #pragma unroll
            for (int r = 0; r < 4; ++r) {
                const int prow = mt * 16 + g * 4 + r;
                if (prow < 361) {
                    plane3h[prow * 24 + col] = (half_t)fmaxf(c0[r] + bias0, 0.f);
                    if (col < 8)
                        plane3h[prow * 24 + 16 + col] = (half_t)fmaxf(c1[r] + bias1, 0.f);
                }
            }
        }
    }
    __syncthreads();

    // ---- conv4 (MFMA): 24->30, 19x19 -> 16x16; stage in LDS ----
    {
        half8_t B4f[12][2];                      // loaded HERE
        const half8_t* Fv = (const half8_t*)F4;
        #pragma unroll
        for (int s = 0; s < 12; ++s) {
            B4f[s][0] = Fv[(s * 2 + 0) * 64 + l];
            B4f[s][1] = Fv[(s * 2 + 1) * 64 + l];
        }
        const float bias0 = b4[col];
        const float bias1 = (16 + col < 30) ? b4[16 + col] : 0.f;
        #pragma unroll 1
        for (int mt = wave; mt < 16; mt += 4) {
            const int pos = mt * 16 + col;
            const int py = pos >> 4, px = pos & 15;
            const char* Ab = plane1b + (py * 19 + px) * 48 + g * 16;   // plane3
            f32x4 c0 = {0.f, 0.f, 0.f, 0.f}, c1 = {0.f, 0.f, 0.f, 0.f};
            #pragma unroll
            for (int s = 0; s < 12; ++s) {
                const half8_t a = *(const half8_t*)(Ab + (s / 3) * 912 + (s % 3) * 64);
                c0 = __builtin_amdgcn_mfma_f32_16x16x32_f16(a, B4f[s][0], c0, 0, 0, 0);
                c1 = __builtin_amdgcn_mfma_f32_16x16x32_f16(a, B4f[s][1], c1, 0, 0, 0);
            }
            #pragma unroll
            for (int r = 0; r < 4; ++r) {
                const int prow = mt * 16 + g * 4 + r;   // < 256
                stage[prow * 32 + col] = (half_t)fmaxf(c0[r] + bias0, 0.f);
                if (col < 14)
                    stage[prow * 32 + 16 + col] = (half_t)fmaxf(c1[r] + bias1, 0.f);
            }
        }
        // coord channels (half2 per thread)
        half2_t cc;
        cc[0] = (half_t)((float)(tid & 15) * 0.0625f);
        cc[1] = (half_t)((float)(tid >> 4) * 0.0625f);
        *(half2_t*)&stage[tid * 32 + 30] = cc;
    }
    __syncthreads();

    // ---- coalesced copy LDS stage -> hbuf (full 64B lines) ----
    {
        const float4* sst  = (const float4*)stage;
        float4* gdst = (float4*)(hout + (size_t)b * 8192);
        #pragma unroll
        for (int k2 = 0; k2 < 4; ++k2)
            gdst[tid + 256 * k2] = sst[tid + 256 * k2];
    }
}

// ===========================================================================
__device__ __forceinline__ void block_reduce2(float& s1, float& s2, float* red)
{
    #pragma unroll
    for (int off = 32; off > 0; off >>= 1) {
        s1 += __shfl_down(s1, off);
        s2 += __shfl_down(s2, off);
    }
    const int lane = threadIdx.x & 63;
    const int wid  = threadIdx.x >> 6;
    if (lane == 0) { red[wid * 2] = s1; red[wid * 2 + 1] = s2; }
    __syncthreads();
    s1 = red[0] + red[2] + red[4] + red[6];
    s2 = red[1] + red[3] + red[5] + red[7];
    __syncthreads();
}

// Vectorized 36-half row read (rows are 16B-aligned: stride 96B = 6x16B).
__device__ __forceinline__ void read_row36(const half_t* rp, float* rv)
{
    #pragma unroll
    for (int i = 0; i < 4; ++i) {
        const half8_t v = *(const half8_t*)(rp + 8 * i);
        #pragma unroll
        for (int jj = 0; jj < 8; ++jj) rv[8 * i + jj] = (float)v[jj];
    }
    const half4_t v4 = *(const half4_t*)(rp + 32);
    #pragma unroll
    for (int jj = 0; jj < 4; ++jj) rv[32 + jj] = (float)v4[jj];
}

// ===========================================================================
// Attention + head, full-MFMA version.
// LDS regions:
//   Qbuf [256][48] fp16 (24576B) : proj scratch -> Q rows -> att rows
//   Kbuf [256][48] fp16 (24576B) : K rows
//   Vt   [48][256]  fp16 (24576B) : V^T, XOR-swizzled (halfidx ^ ((feat&15)<<2))
// This round: vectorized row reads (u16 -> b128) + widened Vt swizzle.
// ===========================================================================
__global__ __launch_bounds__(256, 2) void attn_head_kernel(
    const half_t* __restrict__ hbuf,
    const float* __restrict__ kW, const float* __restrict__ kb,
    const float* __restrict__ qW, const float* __restrict__ qb,
    const float* __restrict__ vW, const float* __restrict__ vb,
    const float* __restrict__ kg, const float* __restrict__ kbeta,
    const float* __restrict__ qg, const float* __restrict__ qbeta,
    const float* __restrict__ vg, const float* __restrict__ vbeta,
    const float* __restrict__ l1W, const float* __restrict__ l1b,
    const float* __restrict__ l2W, const float* __restrict__ l2b,
    float* __restrict__ out)
{
    __shared__ __attribute__((aligned(16))) char LDS[73728];
    __shared__ float red[8];
    __shared__ float epi[196];     // 4*36 wave-max + 36 final + 10 y + lse

    half_t* Qbuf = (half_t*)LDS;
    half_t* Kbuf = (half_t*)(LDS + 24576);
    half_t* Vt   = (half_t*)(LDS + 49152);

    const int b   = blockIdx.x;
    const int tid = threadIdx.x;
    const int w   = tid >> 6;
    const int l   = tid & 63;
    const int c   = l & 15;
    const int g   = l >> 4;

    // ---- h A-fragments (wave w owns node rows 64w..64w+63) ----
    half8_t hA[4];
    #pragma unroll
    for (int mt = 0; mt < 4; ++mt)
        hA[mt] = *(const half8_t*)(hbuf + ((size_t)b * 256 + 64 * w + 16 * mt + c) * 32 + 8 * g);

    // ---- three projections: K (0), V (1), Q (2) ----
    #pragma unroll 1
    for (int pj = 0; pj < 3; ++pj) {
        const float* W    = (pj == 0) ? kW : (pj == 1) ? vW : qW;
        const float* bias = (pj == 0) ? kb : (pj == 1) ? vb : qb;
        const float* gam  = (pj == 0) ? kg : (pj == 1) ? vg : qg;
        const float* bet  = (pj == 0) ? kbeta : (pj == 1) ? vbeta : qbeta;

        // B-fragments from W [36][32] f32 (rows >=36 zero-padded)
        half8_t Bf[3];
        #pragma unroll
        for (int nt = 0; nt < 3; ++nt) {
            const int row = 16 * nt + c;
            half8_t hb;
            if (row < 36) {
                const float4 w0 = *(const float4*)(W + row * 32 + 8 * g);
                const float4 w1 = *(const float4*)(W + row * 32 + 8 * g + 4);
                hb[0] = (half_t)w0.x; hb[1] = (half_t)w0.y; hb[2] = (half_t)w0.z; hb[3] = (half_t)w0.w;
                hb[4] = (half_t)w1.x; hb[5] = (half_t)w1.y; hb[6] = (half_t)w1.z; hb[7] = (half_t)w1.w;
            } else {
                #pragma unroll
                for (int j = 0; j < 8; ++j) hb[j] = (half_t)0.f;
            }
            Bf[nt] = hb;
        }
        // C init = bias (same for all rows of a column)
        f32x4 acc[4][3];
        #pragma unroll
        for (int nt = 0; nt < 3; ++nt) {
            const int o = 16 * nt + c;
            const float bv = (o < 36) ? bias[o] : 0.f;
            #pragma unroll
            for (int mt = 0; mt < 4; ++mt) acc[mt][nt] = (f32x4){bv, bv, bv, bv};
        }
        #pragma unroll
        for (int mt = 0; mt < 4; ++mt)
            #pragma unroll
            for (int nt = 0; nt < 3; ++nt)
                acc[mt][nt] = __builtin_amdgcn_mfma_f32_16x16x32_f16(hA[mt], Bf[nt], acc[mt][nt], 0, 0, 0);

        // scatter C -> scratch [node][feat48]
        #pragma unroll
        for (int mt = 0; mt < 4; ++mt)
            #pragma unroll
            for (int nt = 0; nt < 3; ++nt)
                #pragma unroll
                for (int r = 0; r < 4; ++r)
                    Qbuf[(64 * w + 16 * mt + 4 * g + r) * 48 + 16 * nt + c] = (half_t)acc[mt][nt][r];
        __syncthreads();

        // per-node joint LayerNorm (thread = node) — vectorized row read
        float rv[36];
        read_row36(Qbuf + tid * 48, rv);
        float s1 = 0.f, s2 = 0.f;
        #pragma unroll
        for (int j = 0; j < 36; ++j) { s1 += rv[j]; s2 += rv[j] * rv[j]; }
        block_reduce2(s1, s2, red);
        const float mu  = s1 * (1.0f / 9216.0f);
        const float var = s2 * (1.0f / 9216.0f) - mu * mu;
        const float rs  = rsqrtf(var + LN_EPS);

        half_t rowb[48];
        #pragma unroll
        for (int j4 = 0; j4 < 9; ++j4) {
            const float4 gm = *(const float4*)(gam + tid * 36 + 4 * j4);
            const float4 bt = *(const float4*)(bet + tid * 36 + 4 * j4);
            float f0 = (rv[4*j4+0] - mu) * rs * gm.x + bt.x;
            float f1 = (rv[4*j4+1] - mu) * rs * gm.y + bt.y;
            float f2 = (rv[4*j4+2] - mu) * rs * gm.z + bt.z;
            float f3 = (rv[4*j4+3] - mu) * rs * gm.w + bt.w;
            if (pj == 2) { f0 *= (1.0f/6.0f); f1 *= (1.0f/6.0f); f2 *= (1.0f/6.0f); f3 *= (1.0f/6.0f); }
            rowb[4*j4+0] = (half_t)f0; rowb[4*j4+1] = (half_t)f1;
            rowb[4*j4+2] = (half_t)f2; rowb[4*j4+3] = (half_t)f3;
        }
        #pragma unroll
        for (int j = 36; j < 48; ++j) rowb[j] = (half_t)0.f;

        if (pj == 0) {
            #pragma unroll
            for (int i = 0; i < 6; ++i)
                *(half8_t*)(Kbuf + tid * 48 + 8 * i) = *(half8_t*)&rowb[8 * i];
        } else if (pj == 1) {
            #pragma unroll
            for (int j = 0; j < 36; ++j)
                Vt[j * 256 + (tid ^ ((j & 15) << 2))] = rowb[j];
        } else {
            #pragma unroll
            for (int i = 0; i < 6; ++i)
                *(half8_t*)(Qbuf + tid * 48 + 8 * i) = *(half8_t*)&rowb[8 * i];
        }
        __syncthreads();
    }

    // ---- Q fragments (wave-local rows), held in registers ----
    half8_t Qf32[4];
    half4_t Qf16[4];
    #pragma unroll
    for (int nt = 0; nt < 4; ++nt) {
        const int row = 64 * w + 16 * nt + c;
        Qf32[nt] = *(const half8_t*)(Qbuf + row * 48 + 8 * g);
        Qf16[nt] = *(const half4_t*)(Qbuf + row * 48 + 32 + 4 * g);
    }

    // ---- kv-loop: 8 chunks x 32 keys, no barriers ----
    float m[4], lsum[4];
    f32x4 att[3][4];
    #pragma unroll
    for (int nt = 0; nt < 4; ++nt) {
        m[nt] = -1e30f; lsum[nt] = 0.f;
        #pragma unroll
        for (int mt2 = 0; mt2 < 3; ++mt2) att[mt2][nt] = (f32x4){0.f, 0.f, 0.f, 0.f};
    }

    #pragma unroll 1
    for (int ch = 0; ch < 8; ++ch) {
        half8_t Ka32[2];
        half4_t Ka16[2];
        #pragma unroll
        for (int mt = 0; mt < 2; ++mt) {
            const int row = 32 * ch + 16 * mt + c;
            Ka32[mt] = *(const half8_t*)(Kbuf + row * 48 + 8 * g);
            Ka16[mt] = *(const half4_t*)(Kbuf + row * 48 + 32 + 4 * g);
        }
        half4_t Va[3][2];
        #pragma unroll
        for (int mt2 = 0; mt2 < 3; ++mt2)
            #pragma unroll
            for (int kc = 0; kc < 2; ++kc)
                Va[mt2][kc] = *(const half4_t*)(Vt + (16 * mt2 + c) * 256 +
                                ((32 * ch + 16 * kc + 4 * g) ^ ((c & 15) << 2)));

        // S^T chunk: rows = keys, cols = qrows
        f32x4 S[2][4];
        #pragma unroll
        for (int mt = 0; mt < 2; ++mt)
            #pragma unroll
            for (int nt = 0; nt < 4; ++nt) {
                f32x4 z = {0.f, 0.f, 0.f, 0.f};
                z = __builtin_amdgcn_mfma_f32_16x16x32_f16(Ka32[mt], Qf32[nt], z, 0, 0, 0);
                z = __builtin_amdgcn_mfma_f32_16x16x16f16(Ka16[mt], Qf16[nt], z, 0, 0, 0);
                S[mt][nt] = z;
            }

        // online softmax + PV per qrow-tile
        #pragma unroll
        for (int nt = 0; nt < 4; ++nt) {
            float cm = S[0][nt][0];
            cm = fmaxf(cm, S[0][nt][1]); cm = fmaxf(cm, S[0][nt][2]); cm = fmaxf(cm, S[0][nt][3]);
            cm = fmaxf(cm, S[1][nt][0]); cm = fmaxf(cm, S[1][nt][1]);
            cm = fmaxf(cm, S[1][nt][2]); cm = fmaxf(cm, S[1][nt][3]);
            cm = fmaxf(cm, __shfl_xor(cm, 16));
            cm = fmaxf(cm, __shfl_xor(cm, 32));
            const float newm  = fmaxf(m[nt], cm);
            const float alpha = __expf(m[nt] - newm);
            m[nt] = newm;
            lsum[nt] *= alpha;
            #pragma unroll
            for (int mt2 = 0; mt2 < 3; ++mt2) att[mt2][nt] *= alpha;

            half4_t P[2];
            #pragma unroll
            for (int mt = 0; mt < 2; ++mt) {
                const float p0 = __expf(S[mt][nt][0] - newm);
                const float p1 = __expf(S[mt][nt][1] - newm);
                const float p2 = __expf(S[mt][nt][2] - newm);
                const float p3 = __expf(S[mt][nt][3] - newm);
                lsum[nt] += (p0 + p1) + (p2 + p3);
                half4_t pp;
                pp[0] = (half_t)p0; pp[1] = (half_t)p1; pp[2] = (half_t)p2; pp[3] = (half_t)p3;
                P[mt] = pp;
            }
            #pragma unroll
            for (int mt2 = 0; mt2 < 3; ++mt2) {
                att[mt2][nt] = __builtin_amdgcn_mfma_f32_16x16x16f16(Va[mt2][0], P[0], att[mt2][nt], 0, 0, 0);
                att[mt2][nt] = __builtin_amdgcn_mfma_f32_16x16x16f16(Va[mt2][1], P[1], att[mt2][nt], 0, 0, 0);
            }
        }
    }

    // ---- finalize att -> Qbuf rows ----
    #pragma unroll
    for (int nt = 0; nt < 4; ++nt) {
        float lt = lsum[nt];
        lt += __shfl_xor(lt, 16);
        lt += __shfl_xor(lt, 32);
        const float inv = 1.0f / lt;
        const int row = 64 * w + 16 * nt + c;
        #pragma unroll
        for (int mt2 = 0; mt2 < 2; ++mt2)
            #pragma unroll
            for (int r = 0; r < 4; ++r)
                Qbuf[row * 48 + 16 * mt2 + 4 * g + r] = (half_t)(att[mt2][nt][r] * inv);
        if (g == 0) {
            #pragma unroll
            for (int r = 0; r < 4; ++r)
                Qbuf[row * 48 + 32 + r] = (half_t)(att[2][nt][r] * inv);
        }
    }
    __syncthreads();

    // ---- epilogue: l1+ReLU, joint LN, node-max (wave butterfly), head ----
    float at[36];
    read_row36(Qbuf + tid * 48, at);

    float a2[36];
    #pragma unroll
    for (int jj = 0; jj < 36; ++jj) {
        float s = l1b[jj];
        #pragma unroll
        for (int d = 0; d < 36; ++d) s += at[d] * l1W[jj * 36 + d];
        a2[jj] = fmaxf(s, 0.f);
    }

    float s1 = 0.f, s2 = 0.f;
    #pragma unroll
    for (int j = 0; j < 36; ++j) { s1 += a2[j]; s2 += a2[j] * a2[j]; }
    block_reduce2(s1, s2, red);
    const float mu  = s1 * (1.0f / 9216.0f);
    const float rs  = rsqrtf(s2 * (1.0f / 9216.0f) - mu * mu + LN_EPS);

    float a3[36];
    #pragma unroll
    for (int j = 0; j < 36; ++j) a3[j] = (a2[j] - mu) * rs;

    // wave-level max butterfly over 64 nodes
    #pragma unroll
    for (int off = 1; off < 64; off <<= 1)
        #pragma unroll
        for (int j = 0; j < 36; ++j)
            a3[j] = fmaxf(a3[j], __shfl_xor(a3[j], off));
    if (l == 0) {
        #pragma unroll
        for (int j = 0; j < 36; ++j) epi[w * 36 + j] = a3[j];
    }
    __syncthreads();
    if (tid < 36)
        epi[144 + tid] = fmaxf(fmaxf(epi[tid], epi[36 + tid]),
                               fmaxf(epi[72 + tid], epi[108 + tid]));
    __syncthreads();
    if (tid < 10) {
        float y = l2b[tid];
        #pragma unroll
        for (int j = 0; j < 36; ++j) y += epi[144 + j] * l2W[tid * 36 + j];
        epi[180 + tid] = y;
    }
    __syncthreads();
    if (tid == 0) {
        float mx = epi[180];
        #pragma unroll
        for (int cc = 1; cc < 10; ++cc) mx = fmaxf(mx, epi[180 + cc]);
        float se = 0.f;
        #pragma unroll
        for (int cc = 0; cc < 10; ++cc) se += __expf(epi[180 + cc] - mx);
        const float lse = mx + logf(se);
        #pragma unroll
        for (int cc = 0; cc < 10; ++cc) out[b * 10 + cc] = epi[180 + cc] - lse;
    }
}

// ===========================================================================
extern "C" void kernel_launch(void* const* d_in, const int* in_sizes, int n_in,
                              void* d_out, int out_size, void* d_ws, size_t ws_size,
                              hipStream_t stream)
{
    const float* x     = (const float*)d_in[0];
    const float* w1    = (const float*)d_in[1];
    const float* b1    = (const float*)d_in[2];
    const float* w2    = (const float*)d_in[3];
    const float* b2    = (const float*)d_in[4];
    const float* w3    = (const float*)d_in[5];
    const float* b3    = (const float*)d_in[6];
    const float* w4    = (const float*)d_in[7];
    const float* b4    = (const float*)d_in[8];
    const float* kW    = (const float*)d_in[9];
    const float* kb    = (const float*)d_in[10];
    const float* qW    = (const float*)d_in[11];
    const float* qb    = (const float*)d_in[12];
    const float* vW    = (const float*)d_in[13];
    const float* vb    = (const float*)d_in[14];
    const float* kg    = (const float*)d_in[15];
    const float* kbeta = (const float*)d_in[16];
    const float* qg    = (const float*)d_in[17];
    const float* qbeta = (const float*)d_in[18];
    const float* vg    = (const float*)d_in[19];
    const float* vbeta = (const float*)d_in[20];
    const float* l1W   = (const float*)d_in[21];
    const float* l1b   = (const float*)d_in[22];
    const float* l2W   = (const float*)d_in[23];
    const float* l2b   = (const float*)d_in[24];

    const int B = in_sizes[0] / (28 * 28);            // 2048
    half_t* hbuf = (half_t*)d_ws;                     // [B,256,32] fp16 = 33.5 MB
    half_t* F2 = (half_t*)((char*)d_ws + 33554432);
    half_t* F3 = F2 + 8192;
    half_t* F4 = F3 + 12288;

    prep_weights_kernel<<<dim3(64), dim3(256), 0, stream>>>(w2, w3, w4, F2, F3, F4);
    conv_fused_kernel<<<dim3(B), dim3(256), 0, stream>>>(
        x, w1, b1, b2, b3, b4, F2, F3, F4, hbuf);
    attn_head_kernel<<<dim3(B), dim3(256), 0, stream>>>(
        hbuf, kW, kb, qW, qb, vW, vb,
        kg, kbeta, qg, qbeta, vg, vbeta,
        l1W, l1b, l2W, l2b, (float*)d_out);
}

// Round 10
// 262.298 us; speedup vs baseline: 1.1428x; 1.1428x over previous
//
#include <hip/hip_runtime.h>
#include <math.h>

#define LN_EPS 1e-5f

typedef _Float16 half_t;
typedef _Float16 half8_t __attribute__((ext_vector_type(8)));
typedef _Float16 half4_t __attribute__((ext_vector_type(4)));
typedef _Float16 half2_t __attribute__((ext_vector_type(2)));
typedef float f32x4 __attribute__((ext_vector_type(4)));

// ===========================================================================
// Weight-prep: reorder conv weights into MFMA B-fragment order (fp16).
// ===========================================================================
__global__ void prep_weights_kernel(const float* __restrict__ w2,
                                    const float* __restrict__ w3,
                                    const float* __restrict__ w4,
                                    half_t* __restrict__ F2,
                                    half_t* __restrict__ F3,
                                    half_t* __restrict__ F4)
{
    const int bid = blockIdx.x;
    const int t   = threadIdx.x;
    const int flat0 = t * 2;
    const int l  = flat0 >> 3;
    const int j0 = flat0 & 7;

    int layer, sn;
    half_t* dst;
    if (bid < 16)      { layer = 2; sn = bid;      dst = F2; }
    else if (bid < 40) { layer = 3; sn = bid - 16; dst = F3; }
    else               { layer = 4; sn = bid - 40; dst = F4; }
    const int s  = sn >> 1;
    const int nt = sn & 1;
    const int oc = nt * 16 + (l & 15);

    float v[2];
    #pragma unroll
    for (int u = 0; u < 2; ++u) {
        const int j = j0 + u;
        const int k = s * 32 + ((l >> 4) * 8) + j;
        float val = 0.f;
        if (layer == 2) {
            const int ky = k >> 6, rem = k & 63, kx = rem >> 4, ic = rem & 15;
            if (oc < 20) val = w2[(oc * 16 + ic) * 16 + ky * 4 + kx];
        } else if (layer == 3) {
            const int ky = k / 96, rem = k % 96, kx = rem / 24, ic = rem % 24;
            if (oc < 24 && ic < 20) val = w3[(oc * 20 + ic) * 16 + ky * 4 + kx];
        } else {
            const int ky = k / 96, rem = k % 96, kx = rem / 24, ic = rem % 24;
            if (oc < 30) val = w4[(oc * 24 + ic) * 16 + ky * 4 + kx];
        }
        v[u] = val;
    }
    half2_t outv;
    outv[0] = (half_t)v[0];
    outv[1] = (half_t)v[1];
    *(half2_t*)&dst[(sn * 64 + l) * 8 + j0] = outv;
}

// ===========================================================================
// Fused conv stack, MFMA implicit GEMM (unchanged — passing, ~100us).
// ===========================================================================
__global__ __launch_bounds__(256, 2) void conv_fused_kernel(
    const float* __restrict__ x,
    const float* __restrict__ w1, const float* __restrict__ b1,
    const float* __restrict__ b2, const float* __restrict__ b3,
    const float* __restrict__ b4,
    const half_t* __restrict__ F2, const half_t* __restrict__ F3,
    const half_t* __restrict__ F4,
    half_t* __restrict__ hout)
{
    __shared__ __attribute__((aligned(16))) char LBUF[45280];
    float*  xw = (float*)LBUF;
    char*   plane2b = LBUF;                 // conv2 out / conv4 stage region
    char*   plane1b = LBUF + 23232;         // conv1 out / conv3 out region
    half_t* plane2h = (half_t*)plane2b;
    half_t* plane1h = (half_t*)plane1b;
    half_t* plane3h = (half_t*)plane1b;
    half_t* stage   = (half_t*)plane2b;     // conv4 staging [256][32] fp16

    const int b    = blockIdx.x;
    const int tid  = threadIdx.x;
    const int wave = tid >> 6;
    const int l    = tid & 63;
    const int col  = l & 15;
    const int g    = l >> 4;

    {
        const float4* gx = (const float4*)(x + (size_t)b * 784);
        if (tid < 196) ((float4*)xw)[tid] = gx[tid];
        const int i = tid;
        if (i < 256) xw[784 + (i & 15) * 16 + (i >> 4)] = w1[i];
        if (tid < 16) xw[1040 + tid] = b1[tid];
    }
    __syncthreads();

    // ---- conv1 (fp32 VALU): 1->16, 28x28 -> 25x25, HWC fp16 out ----
    {
        const float* xs  = xw;
        const float* w1s = xw + 784;
        const float* b1s = xw + 1040;
        const int p0 = tid, p1 = tid + 256;
        const bool v2 = (tid + 512) < 625;
        const int p2 = v2 ? tid + 512 : 624;
        const int y0 = p0 / 25, x0 = p0 % 25;
        const int y1 = p1 / 25, x1 = p1 % 25;
        const int y2 = p2 / 25, x2 = p2 % 25;
        float a0[16], a1[16], a2[16];
        #pragma unroll
        for (int oc = 0; oc < 16; ++oc) { const float bb = b1s[oc]; a0[oc] = bb; a1[oc] = bb; a2[oc] = bb; }
        #pragma unroll
        for (int k = 0; k < 16; ++k) {
            const int ky = k >> 2, kx = k & 3;
            const float i0 = xs[(y0 + ky) * 28 + x0 + kx];
            const float i1 = xs[(y1 + ky) * 28 + x1 + kx];
            const float i2 = xs[(y2 + ky) * 28 + x2 + kx];
            #pragma unroll
            for (int oc4 = 0; oc4 < 4; ++oc4) {
                const float4 wv = *(const float4*)&w1s[k * 16 + oc4 * 4];
                const float wq[4] = {wv.x, wv.y, wv.z, wv.w};
                #pragma unroll
                for (int q = 0; q < 4; ++q) {
                    const int oc = oc4 * 4 + q;
                    a0[oc] += i0 * wq[q]; a1[oc] += i1 * wq[q]; a2[oc] += i2 * wq[q];
                }
            }
        }
        __syncthreads();
        #pragma unroll
        for (int i2_ = 0; i2_ < 8; ++i2_) {
            half2_t h0, h1;
            h0[0] = (half_t)fmaxf(a0[2 * i2_], 0.f); h0[1] = (half_t)fmaxf(a0[2 * i2_ + 1], 0.f);
            h1[0] = (half_t)fmaxf(a1[2 * i2_], 0.f); h1[1] = (half_t)fmaxf(a1[2 * i2_ + 1], 0.f);
            *(half2_t*)&plane1h[p0 * 16 + 2 * i2_] = h0;
            *(half2_t*)&plane1h[p1 * 16 + 2 * i2_] = h1;
        }
        if (v2) {
            #pragma unroll
            for (int i2_ = 0; i2_ < 8; ++i2_) {
                half2_t h2v;
                h2v[0] = (half_t)fmaxf(a2[2 * i2_], 0.f); h2v[1] = (half_t)fmaxf(a2[2 * i2_ + 1], 0.f);
                *(half2_t*)&plane1h[p2 * 16 + 2 * i2_] = h2v;
            }
        }
    }
    __syncthreads();

    // ---- conv2 (MFMA): 16->20(pad24), 25x25 -> 22x22, K=256 (8 steps) ----
    {
        half8_t B2f[8][2];
        const half8_t* Fv = (const half8_t*)F2;
        #pragma unroll
        for (int s = 0; s < 8; ++s) {
            B2f[s][0] = Fv[(s * 2 + 0) * 64 + l];
            B2f[s][1] = Fv[(s * 2 + 1) * 64 + l];
        }
        const float bias0 = b2[col];
        const float bias1 = (16 + col < 20) ? b2[16 + col] : 0.f;
        #pragma unroll 1
        for (int mt = wave; mt < 31; mt += 4) {
            const int pos = mt * 16 + col;
            const int py = pos / 22, px = pos - py * 22;
            const char* Ab = plane1b + (py * 25 + px) * 32 + g * 16;
            f32x4 c0 = {0.f, 0.f, 0.f, 0.f}, c1 = {0.f, 0.f, 0.f, 0.f};
            #pragma unroll
            for (int s = 0; s < 8; ++s) {
                const half8_t a = *(const half8_t*)(Ab + (s >> 1) * 800 + (s & 1) * 64);
                c0 = __builtin_amdgcn_mfma_f32_16x16x32_f16(a, B2f[s][0], c0, 0, 0, 0);
                c1 = __builtin_amdgcn_mfma_f32_16x16x32_f16(a, B2f[s][1], c1, 0, 0, 0);
            }
            #pragma unroll
            for (int r = 0; r < 4; ++r) {
                const int prow = mt * 16 + g * 4 + r;
                if (prow < 484) {
                    plane2h[prow * 24 + col] = (half_t)fmaxf(c0[r] + bias0, 0.f);
                    if (col < 8) {
                        const float v = (col < 4) ? fmaxf(c1[r] + bias1, 0.f) : 0.f;
                        plane2h[prow * 24 + 16 + col] = (half_t)v;
                    }
                }
            }
        }
    }
    __syncthreads();

    // ---- conv3 (MFMA): 24(in,pad)->24, 22x22 -> 19x19, K=384 (12 steps) ----
    {
        half8_t B3f[12][2];
        const half8_t* Fv = (const half8_t*)F3;
        #pragma unroll
        for (int s = 0; s < 12; ++s) {
            B3f[s][0] = Fv[(s * 2 + 0) * 64 + l];
            B3f[s][1] = Fv[(s * 2 + 1) * 64 + l];
        }
        const float bias0 = b3[col];
        const float bias1 = b3[16 + (col & 7)];
        #pragma unroll 1
        for (int mt = wave; mt < 23; mt += 4) {
            const int pos = mt * 16 + col;
            const int py = pos / 19, px = pos - py * 19;
            const char* Ab = plane2b + (py * 22 + px) * 48 + g * 16;
            f32x4 c0 = {0.f, 0.f, 0.f, 0.f}, c1 = {0.f, 0.f, 0.f, 0.f};
            #pragma unroll
            for (int s = 0; s < 12; ++s) {
                const half8_t a = *(const half8_t*)(Ab + (s / 3) * 1056 + (s % 3) * 64);
                c0 = __builtin_amdgcn_mfma_f32_16x16x32_f16(a, B3f[s][0], c0, 0, 0, 0);
                c1 = __builtin_amdgcn_mfma_f32_16x16x32_f16(a, B3f[s][1], c1, 0, 0, 0);
            }
            #pragma unroll
            for (int r = 0; r < 4; ++r) {
                const int prow = mt * 16 + g * 4 + r;
                if (prow < 361) {
                    plane3h[prow * 24 + col] = (half_t)fmaxf(c0[r] + bias0, 0.f);
                    if (col < 8)
                        plane3h[prow * 24 + 16 + col] = (half_t)fmaxf(c1[r] + bias1, 0.f);
                }
            }
        }
    }
    __syncthreads();

    // ---- conv4 (MFMA): 24->30, 19x19 -> 16x16; stage in LDS ----
    {
        half8_t B4f[12][2];
        const half8_t* Fv = (const half8_t*)F4;
        #pragma unroll
        for (int s = 0; s < 12; ++s) {
            B4f[s][0] = Fv[(s * 2 + 0) * 64 + l];
            B4f[s][1] = Fv[(s * 2 + 1) * 64 + l];
        }
        const float bias0 = b4[col];
        const float bias1 = (16 + col < 30) ? b4[16 + col] : 0.f;
        #pragma unroll 1
        for (int mt = wave; mt < 16; mt += 4) {
            const int pos = mt * 16 + col;
            const int py = pos >> 4, px = pos & 15;
            const char* Ab = plane1b + (py * 19 + px) * 48 + g * 16;   // plane3
            f32x4 c0 = {0.f, 0.f, 0.f, 0.f}, c1 = {0.f, 0.f, 0.f, 0.f};
            #pragma unroll
            for (int s = 0; s < 12; ++s) {
                const half8_t a = *(const half8_t*)(Ab + (s / 3) * 912 + (s % 3) * 64);
                c0 = __builtin_amdgcn_mfma_f32_16x16x32_f16(a, B4f[s][0], c0, 0, 0, 0);
                c1 = __builtin_amdgcn_mfma_f32_16x16x32_f16(a, B4f[s][1], c1, 0, 0, 0);
            }
            #pragma unroll
            for (int r = 0; r < 4; ++r) {
                const int prow = mt * 16 + g * 4 + r;   // < 256
                stage[prow * 32 + col] = (half_t)fmaxf(c0[r] + bias0, 0.f);
                if (col < 14)
                    stage[prow * 32 + 16 + col] = (half_t)fmaxf(c1[r] + bias1, 0.f);
            }
        }
        half2_t cc;
        cc[0] = (half_t)((float)(tid & 15) * 0.0625f);
        cc[1] = (half_t)((float)(tid >> 4) * 0.0625f);
        *(half2_t*)&stage[tid * 32 + 30] = cc;
    }
    __syncthreads();

    {
        const float4* sst  = (const float4*)stage;
        float4* gdst = (float4*)(hout + (size_t)b * 8192);
        #pragma unroll
        for (int k2 = 0; k2 < 4; ++k2)
            gdst[tid + 256 * k2] = sst[tid + 256 * k2];
    }
}

// ===========================================================================
__device__ __forceinline__ void block_reduce2(float& s1, float& s2, float* red)
{
    #pragma unroll
    for (int off = 32; off > 0; off >>= 1) {
        s1 += __shfl_down(s1, off);
        s2 += __shfl_down(s2, off);
    }
    const int lane = threadIdx.x & 63;
    const int wid  = threadIdx.x >> 6;
    if (lane == 0) { red[wid * 2] = s1; red[wid * 2 + 1] = s2; }
    __syncthreads();
    s1 = red[0] + red[2] + red[4] + red[6];
    s2 = red[1] + red[3] + red[5] + red[7];
    __syncthreads();
}

// Projection GEMM (bias in C-init) + scatter to [node][feat48] rows — the
// R8-verified pattern, factored (identical body).
__device__ __forceinline__ void proj_scatter(const half8_t hA[4],
                                             const float* __restrict__ W,
                                             const float* __restrict__ bias,
                                             half_t* scr, int w, int c, int g)
{
    half8_t Bf[3];
    #pragma unroll
    for (int nt = 0; nt < 3; ++nt) {
        const int row = 16 * nt + c;
        half8_t hb;
        if (row < 36) {
            const float4 w0 = *(const float4*)(W + row * 32 + 8 * g);
            const float4 w1 = *(const float4*)(W + row * 32 + 8 * g + 4);
            hb[0] = (half_t)w0.x; hb[1] = (half_t)w0.y; hb[2] = (half_t)w0.z; hb[3] = (half_t)w0.w;
            hb[4] = (half_t)w1.x; hb[5] = (half_t)w1.y; hb[6] = (half_t)w1.z; hb[7] = (half_t)w1.w;
        } else {
            #pragma unroll
            for (int j = 0; j < 8; ++j) hb[j] = (half_t)0.f;
        }
        Bf[nt] = hb;
    }
    f32x4 acc[4][3];
    #pragma unroll
    for (int nt = 0; nt < 3; ++nt) {
        const int o = 16 * nt + c;
        const float bv = (o < 36) ? bias[o] : 0.f;
        #pragma unroll
        for (int mt = 0; mt < 4; ++mt) acc[mt][nt] = (f32x4){bv, bv, bv, bv};
    }
    #pragma unroll
    for (int mt = 0; mt < 4; ++mt)
        #pragma unroll
        for (int nt = 0; nt < 3; ++nt)
            acc[mt][nt] = __builtin_amdgcn_mfma_f32_16x16x32_f16(hA[mt], Bf[nt], acc[mt][nt], 0, 0, 0);
    #pragma unroll
    for (int mt = 0; mt < 4; ++mt)
        #pragma unroll
        for (int nt = 0; nt < 3; ++nt)
            #pragma unroll
            for (int r = 0; r < 4; ++r)
                scr[(64 * w + 16 * mt + 4 * g + r) * 48 + 16 * nt + c] = (half_t)acc[mt][nt][r];
}

// Per-node joint LN: scalar row read (R8-verified), stats via block_reduce2,
// affine+scale into rowb[48] (36..47 zeroed).
__device__ __forceinline__ void ln_row(const half_t* buf, int tid,
                                       const float* __restrict__ gam,
                                       const float* __restrict__ bet,
                                       float scale, float* red, half_t* rowb)
{
    float rv[36];
    {
        const half_t* rp = buf + tid * 48;
        #pragma unroll
        for (int j = 0; j < 36; ++j) rv[j] = (float)rp[j];
    }
    float s1 = 0.f, s2 = 0.f;
    #pragma unroll
    for (int j = 0; j < 36; ++j) { s1 += rv[j]; s2 += rv[j] * rv[j]; }
    block_reduce2(s1, s2, red);
    const float mu  = s1 * (1.0f / 9216.0f);
    const float var = s2 * (1.0f / 9216.0f) - mu * mu;
    const float rs  = rsqrtf(var + LN_EPS);
    #pragma unroll
    for (int j4 = 0; j4 < 9; ++j4) {
        const float4 gm = *(const float4*)(gam + tid * 36 + 4 * j4);
        const float4 bt = *(const float4*)(bet + tid * 36 + 4 * j4);
        rowb[4*j4+0] = (half_t)(((rv[4*j4+0] - mu) * rs * gm.x + bt.x) * scale);
        rowb[4*j4+1] = (half_t)(((rv[4*j4+1] - mu) * rs * gm.y + bt.y) * scale);
        rowb[4*j4+2] = (half_t)(((rv[4*j4+2] - mu) * rs * gm.z + bt.z) * scale);
        rowb[4*j4+3] = (half_t)(((rv[4*j4+3] - mu) * rs * gm.w + bt.w) * scale);
    }
    #pragma unroll
    for (int j = 36; j < 48; ++j) rowb[j] = (half_t)0.f;
}

// ===========================================================================
// Attention + head, full-MFMA. Two time-shared 24KB buffers -> 3 blocks/CU:
//   BufA [256][48]: Q rows -> K rows -> att rows
//   BufB [256][48]: V raw -> Vt [48][256] swizzled (in-place transpose)
// ===========================================================================
__global__ __launch_bounds__(256, 3) void attn_head_kernel(
    const half_t* __restrict__ hbuf,
    const float* __restrict__ kW, const float* __restrict__ kb,
    const float* __restrict__ qW, const float* __restrict__ qb,
    const float* __restrict__ vW, const float* __restrict__ vb,
    const float* __restrict__ kg, const float* __restrict__ kbeta,
    const float* __restrict__ qg, const float* __restrict__ qbeta,
    const float* __restrict__ vg, const float* __restrict__ vbeta,
    const float* __restrict__ l1W, const float* __restrict__ l1b,
    const float* __restrict__ l2W, const float* __restrict__ l2b,
    float* __restrict__ out)
{
    __shared__ __attribute__((aligned(16))) char LDS[49152];
    __shared__ float red[8];
    __shared__ float epi[196];

    half_t* BufA = (half_t*)LDS;
    half_t* BufB = (half_t*)(LDS + 24576);
    half_t* Vt   = (half_t*)(LDS + 24576);

    const int b   = blockIdx.x;
    const int tid = threadIdx.x;
    const int w   = tid >> 6;
    const int l   = tid & 63;
    const int c   = l & 15;
    const int g   = l >> 4;

    // ---- h A-fragments (wave w owns node rows 64w..64w+63) ----
    half8_t hA[4];
    #pragma unroll
    for (int mt = 0; mt < 4; ++mt)
        hA[mt] = *(const half8_t*)(hbuf + ((size_t)b * 256 + 64 * w + 16 * mt + c) * 32 + 8 * g);

    // ---- Q -> BufA, V -> BufB (raw + bias) ----
    proj_scatter(hA, qW, qb, BufA, w, c, g);
    proj_scatter(hA, vW, vb, BufB, w, c, g);
    __syncthreads();                                   // S1: scatters visible

    // ---- Q LN (x 1/6), in-place own-row write ----
    {
        half_t rowb[48];
        ln_row(BufA, tid, qg, qbeta, (1.0f / 6.0f), red, rowb);
        #pragma unroll
        for (int i = 0; i < 6; ++i)
            *(half8_t*)(BufA + tid * 48 + 8 * i) = *(half8_t*)&rowb[8 * i];
    }
    // ---- V LN + in-place transpose into Vt ----
    // (ln_row's block_reduce2 barriers fence all raw-row reads before any
    //  transposed write lands in BufB.)
    {
        half_t rowb[48];
        ln_row(BufB, tid, vg, vbeta, 1.0f, red, rowb);
        #pragma unroll
        for (int j = 0; j < 48; ++j) {
            const half_t v = (j < 36) ? rowb[j] : (half_t)0.f;
            Vt[j * 256 + (tid ^ ((j & 7) << 2))] = v;
        }
    }
    __syncthreads();                                   // S2: Q rows + Vt visible

    // ---- Q fragments (wave-local rows) -> registers ----
    half8_t Qf32[4];
    half4_t Qf16[4];
    #pragma unroll
    for (int nt = 0; nt < 4; ++nt) {
        const int row = 64 * w + 16 * nt + c;
        Qf32[nt] = *(const half8_t*)(BufA + row * 48 + 8 * g);
        Qf16[nt] = *(const half4_t*)(BufA + row * 48 + 32 + 4 * g);
    }
    __syncthreads();                                   // S3: frag reads done, BufA free

    // ---- K -> BufA (raw), LN in place ----
    proj_scatter(hA, kW, kb, BufA, w, c, g);
    __syncthreads();                                   // S4
    {
        half_t rowb[48];
        ln_row(BufA, tid, kg, kbeta, 1.0f, red, rowb);
        #pragma unroll
        for (int i = 0; i < 6; ++i)
            *(half8_t*)(BufA + tid * 48 + 8 * i) = *(half8_t*)&rowb[8 * i];
    }
    __syncthreads();                                   // S5: K rows visible

    // ---- kv-loop: 8 chunks x 32 keys, no barriers ----
    float m[4], lsum[4];
    f32x4 att[3][4];
    #pragma unroll
    for (int nt = 0; nt < 4; ++nt) {
        m[nt] = -1e30f; lsum[nt] = 0.f;
        #pragma unroll
        for (int mt2 = 0; mt2 < 3; ++mt2) att[mt2][nt] = (f32x4){0.f, 0.f, 0.f, 0.f};
    }

    #pragma unroll 1
    for (int ch = 0; ch < 8; ++ch) {
        half8_t Ka32[2];
        half4_t Ka16[2];
        #pragma unroll
        for (int kt = 0; kt < 2; ++kt) {
            const int row = 32 * ch + 16 * kt + c;
            Ka32[kt] = *(const half8_t*)(BufA + row * 48 + 8 * g);
            Ka16[kt] = *(const half4_t*)(BufA + row * 48 + 32 + 4 * g);
        }
        half4_t Va[3][2];
        #pragma unroll
        for (int mt2 = 0; mt2 < 3; ++mt2)
            #pragma unroll
            for (int kc = 0; kc < 2; ++kc)
                Va[mt2][kc] = *(const half4_t*)(Vt + (16 * mt2 + c) * 256 +
                                ((32 * ch + 16 * kc + 4 * g) ^ ((c & 7) << 2)));

        // S^T chunk: rows = keys, cols = qrows
        f32x4 S[2][4];
        #pragma unroll
        for (int kt = 0; kt < 2; ++kt)
            #pragma unroll
            for (int nt = 0; nt < 4; ++nt) {
                f32x4 z = {0.f, 0.f, 0.f, 0.f};
                z = __builtin_amdgcn_mfma_f32_16x16x32_f16(Ka32[kt], Qf32[nt], z, 0, 0, 0);
                z = __builtin_amdgcn_mfma_f32_16x16x16f16(Ka16[kt], Qf16[nt], z, 0, 0, 0);
                S[kt][nt] = z;
            }

        // online softmax + PV per qrow-tile
        #pragma unroll
        for (int nt = 0; nt < 4; ++nt) {
            float cm = S[0][nt][0];
            cm = fmaxf(cm, S[0][nt][1]); cm = fmaxf(cm, S[0][nt][2]); cm = fmaxf(cm, S[0][nt][3]);
            cm = fmaxf(cm, S[1][nt][0]); cm = fmaxf(cm, S[1][nt][1]);
            cm = fmaxf(cm, S[1][nt][2]); cm = fmaxf(cm, S[1][nt][3]);
            cm = fmaxf(cm, __shfl_xor(cm, 16));
            cm = fmaxf(cm, __shfl_xor(cm, 32));
            const float newm  = fmaxf(m[nt], cm);
            const float alpha = __expf(m[nt] - newm);
            m[nt] = newm;
            lsum[nt] *= alpha;
            #pragma unroll
            for (int mt2 = 0; mt2 < 3; ++mt2) att[mt2][nt] *= alpha;

            half4_t P[2];
            #pragma unroll
            for (int kt = 0; kt < 2; ++kt) {
                const float p0 = __expf(S[kt][nt][0] - newm);
                const float p1 = __expf(S[kt][nt][1] - newm);
                const float p2 = __expf(S[kt][nt][2] - newm);
                const float p3 = __expf(S[kt][nt][3] - newm);
                lsum[nt] += (p0 + p1) + (p2 + p3);
                half4_t pp;
                pp[0] = (half_t)p0; pp[1] = (half_t)p1; pp[2] = (half_t)p2; pp[3] = (half_t)p3;
                P[kt] = pp;
            }
            #pragma unroll
            for (int mt2 = 0; mt2 < 3; ++mt2) {
                att[mt2][nt] = __builtin_amdgcn_mfma_f32_16x16x16f16(Va[mt2][0], P[0], att[mt2][nt], 0, 0, 0);
                att[mt2][nt] = __builtin_amdgcn_mfma_f32_16x16x16f16(Va[mt2][1], P[1], att[mt2][nt], 0, 0, 0);
            }
        }
    }
    __syncthreads();                                   // S6: kv reads of BufA done

    // ---- finalize att -> BufA rows (K dead) ----
    #pragma unroll
    for (int nt = 0; nt < 4; ++nt) {
        float lt = lsum[nt];
        lt += __shfl_xor(lt, 16);
        lt += __shfl_xor(lt, 32);
        const float inv = 1.0f / lt;
        const int row = 64 * w + 16 * nt + c;
        #pragma unroll
        for (int mt2 = 0; mt2 < 2; ++mt2)
            #pragma unroll
            for (int r = 0; r < 4; ++r)
                BufA[row * 48 + 16 * mt2 + 4 * g + r] = (half_t)(att[mt2][nt][r] * inv);
        if (g == 0) {
            #pragma unroll
            for (int r = 0; r < 4; ++r)
                BufA[row * 48 + 32 + r] = (half_t)(att[2][nt][r] * inv);
        }
    }
    __syncthreads();                                   // S7: att rows ready

    // ---- epilogue: l1+ReLU, joint LN, node-max (wave butterfly), head ----
    float at[36];
    {
        const half_t* rp = BufA + tid * 48;
        #pragma unroll
        for (int j = 0; j < 36; ++j) at[j] = (float)rp[j];
    }

    float a2[36];
    #pragma unroll
    for (int jj = 0; jj < 36; ++jj) {
        float s = l1b[jj];
        #pragma unroll
        for (int d = 0; d < 36; ++d) s += at[d] * l1W[jj * 36 + d];
        a2[jj] = fmaxf(s, 0.f);
    }

    float s1 = 0.f, s2 = 0.f;
    #pragma unroll
    for (int j = 0; j < 36; ++j) { s1 += a2[j]; s2 += a2[j] * a2[j]; }
    block_reduce2(s1, s2, red);
    const float mu  = s1 * (1.0f / 9216.0f);
    const float rs  = rsqrtf(s2 * (1.0f / 9216.0f) - mu * mu + LN_EPS);

    float a3[36];
    #pragma unroll
    for (int j = 0; j < 36; ++j) a3[j] = (a2[j] - mu) * rs;

    // wave-level max butterfly over 64 nodes
    #pragma unroll
    for (int off = 1; off < 64; off <<= 1)
        #pragma unroll
        for (int j = 0; j < 36; ++j)
            a3[j] = fmaxf(a3[j], __shfl_xor(a3[j], off));
    if (l == 0) {
        #pragma unroll
        for (int j = 0; j < 36; ++j) epi[w * 36 + j] = a3[j];
    }
    __syncthreads();
    if (tid < 36)
        epi[144 + tid] = fmaxf(fmaxf(epi[tid], epi[36 + tid]),
                               fmaxf(epi[72 + tid], epi[108 + tid]));
    __syncthreads();
    if (tid < 10) {
        float y = l2b[tid];
        #pragma unroll
        for (int j = 0; j < 36; ++j) y += epi[144 + j] * l2W[tid * 36 + j];
        epi[180 + tid] = y;
    }
    __syncthreads();
    if (tid == 0) {
        float mx = epi[180];
        #pragma unroll
        for (int cc = 1; cc < 10; ++cc) mx = fmaxf(mx, epi[180 + cc]);
        float se = 0.f;
        #pragma unroll
        for (int cc = 0; cc < 10; ++cc) se += __expf(epi[180 + cc] - mx);
        const float lse = mx + logf(se);
        #pragma unroll
        for (int cc = 0; cc < 10; ++cc) out[b * 10 + cc] = epi[180 + cc] - lse;
    }
}

// ===========================================================================
extern "C" void kernel_launch(void* const* d_in, const int* in_sizes, int n_in,
                              void* d_out, int out_size, void* d_ws, size_t ws_size,
                              hipStream_t stream)
{
    const float* x     = (const float*)d_in[0];
    const float* w1    = (const float*)d_in[1];
    const float* b1    = (const float*)d_in[2];
    const float* w2    = (const float*)d_in[3];
    const float* b2    = (const float*)d_in[4];
    const float* w3    = (const float*)d_in[5];
    const float* b3    = (const float*)d_in[6];
    const float* w4    = (const float*)d_in[7];
    const float* b4    = (const float*)d_in[8];
    const float* kW    = (const float*)d_in[9];
    const float* kb    = (const float*)d_in[10];
    const float* qW    = (const float*)d_in[11];
    const float* qb    = (const float*)d_in[12];
    const float* vW    = (const float*)d_in[13];
    const float* vb    = (const float*)d_in[14];
    const float* kg    = (const float*)d_in[15];
    const float* kbeta = (const float*)d_in[16];
    const float* qg    = (const float*)d_in[17];
    const float* qbeta = (const float*)d_in[18];
    const float* vg    = (const float*)d_in[19];
    const float* vbeta = (const float*)d_in[20];
    const float* l1W   = (const float*)d_in[21];
    const float* l1b   = (const float*)d_in[22];
    const float* l2W   = (const float*)d_in[23];
    const float* l2b   = (const float*)d_in[24];

    const int B = in_sizes[0] / (28 * 28);            // 2048
    half_t* hbuf = (half_t*)d_ws;                     // [B,256,32] fp16 = 33.5 MB
    half_t* F2 = (half_t*)((char*)d_ws + 33554432);
    half_t* F3 = F2 + 8192;
    half_t* F4 = F3 + 12288;

    prep_weights_kernel<<<dim3(64), dim3(256), 0, stream>>>(w2, w3, w4, F2, F3, F4);
    conv_fused_kernel<<<dim3(B), dim3(256), 0, stream>>>(
        x, w1, b1, b2, b3, b4, F2, F3, F4, hbuf);
    attn_head_kernel<<<dim3(B), dim3(256), 0, stream>>>(
        hbuf, kW, kb, qW, qb, vW, vb,
        kg, kbeta, qg, qbeta, vg, vbeta,
        l1W, l1b, l2W, l2b, (float*)d_out);
}

// Round 12
// 250.149 us; speedup vs baseline: 1.1983x; 1.0486x over previous
//
#include <hip/hip_runtime.h>
#include <math.h>

#define LN_EPS 1e-5f

typedef _Float16 half_t;
typedef _Float16 half8_t __attribute__((ext_vector_type(8)));
typedef _Float16 half4_t __attribute__((ext_vector_type(4)));
typedef _Float16 half2_t __attribute__((ext_vector_type(2)));
typedef float f32x4 __attribute__((ext_vector_type(4)));

// ===========================================================================
// Weight-prep: reorder conv weights into MFMA B-fragment order (fp16).
// ===========================================================================
__global__ void prep_weights_kernel(const float* __restrict__ w2,
                                    const float* __restrict__ w3,
                                    const float* __restrict__ w4,
                                    half_t* __restrict__ F2,
                                    half_t* __restrict__ F3,
                                    half_t* __restrict__ F4)
{
    const int bid = blockIdx.x;
    const int t   = threadIdx.x;
    const int flat0 = t * 2;
    const int l  = flat0 >> 3;
    const int j0 = flat0 & 7;

    int layer, sn;
    half_t* dst;
    if (bid < 16)      { layer = 2; sn = bid;      dst = F2; }
    else if (bid < 40) { layer = 3; sn = bid - 16; dst = F3; }
    else               { layer = 4; sn = bid - 40; dst = F4; }
    const int s  = sn >> 1;
    const int nt = sn & 1;
    const int oc = nt * 16 + (l & 15);

    float v[2];
    #pragma unroll
    for (int u = 0; u < 2; ++u) {
        const int j = j0 + u;
        const int k = s * 32 + ((l >> 4) * 8) + j;
        float val = 0.f;
        if (layer == 2) {
            const int ky = k >> 6, rem = k & 63, kx = rem >> 4, ic = rem & 15;
            if (oc < 20) val = w2[(oc * 16 + ic) * 16 + ky * 4 + kx];
        } else if (layer == 3) {
            const int ky = k / 96, rem = k % 96, kx = rem / 24, ic = rem % 24;
            if (oc < 24 && ic < 20) val = w3[(oc * 20 + ic) * 16 + ky * 4 + kx];
        } else {
            const int ky = k / 96, rem = k % 96, kx = rem / 24, ic = rem % 24;
            if (oc < 30) val = w4[(oc * 24 + ic) * 16 + ky * 4 + kx];
        }
        v[u] = val;
    }
    half2_t outv;
    outv[0] = (half_t)v[0];
    outv[1] = (half_t)v[1];
    *(half2_t*)&dst[(sn * 64 + l) * 8 + j0] = outv;
}

// ===========================================================================
// Fused conv stack, MFMA implicit GEMM (unchanged — passing, ~100us).
// ===========================================================================
__global__ __launch_bounds__(256, 2) void conv_fused_kernel(
    const float* __restrict__ x,
    const float* __restrict__ w1, const float* __restrict__ b1,
    const float* __restrict__ b2, const float* __restrict__ b3,
    const float* __restrict__ b4,
    const half_t* __restrict__ F2, const half_t* __restrict__ F3,
    const half_t* __restrict__ F4,
    half_t* __restrict__ hout)
{
    __shared__ __attribute__((aligned(16))) char LBUF[45280];
    float*  xw = (float*)LBUF;
    char*   plane2b = LBUF;                 // conv2 out / conv4 stage region
    char*   plane1b = LBUF + 23232;         // conv1 out / conv3 out region
    half_t* plane2h = (half_t*)plane2b;
    half_t* plane1h = (half_t*)plane1b;
    half_t* plane3h = (half_t*)plane1b;
    half_t* stage   = (half_t*)plane2b;     // conv4 staging [256][32] fp16

    const int b    = blockIdx.x;
    const int tid  = threadIdx.x;
    const int wave = tid >> 6;
    const int l    = tid & 63;
    const int col  = l & 15;
    const int g    = l >> 4;

    {
        const float4* gx = (const float4*)(x + (size_t)b * 784);
        if (tid < 196) ((float4*)xw)[tid] = gx[tid];
        const int i = tid;
        if (i < 256) xw[784 + (i & 15) * 16 + (i >> 4)] = w1[i];
        if (tid < 16) xw[1040 + tid] = b1[tid];
    }
    __syncthreads();

    // ---- conv1 (fp32 VALU): 1->16, 28x28 -> 25x25, HWC fp16 out ----
    {
        const float* xs  = xw;
        const float* w1s = xw + 784;
        const float* b1s = xw + 1040;
        const int p0 = tid, p1 = tid + 256;
        const bool v2 = (tid + 512) < 625;
        const int p2 = v2 ? tid + 512 : 624;
        const int y0 = p0 / 25, x0 = p0 % 25;
        const int y1 = p1 / 25, x1 = p1 % 25;
        const int y2 = p2 / 25, x2 = p2 % 25;
        float a0[16], a1[16], a2[16];
        #pragma unroll
        for (int oc = 0; oc < 16; ++oc) { const float bb = b1s[oc]; a0[oc] = bb; a1[oc] = bb; a2[oc] = bb; }
        #pragma unroll
        for (int k = 0; k < 16; ++k) {
            const int ky = k >> 2, kx = k & 3;
            const float i0 = xs[(y0 + ky) * 28 + x0 + kx];
            const float i1 = xs[(y1 + ky) * 28 + x1 + kx];
            const float i2 = xs[(y2 + ky) * 28 + x2 + kx];
            #pragma unroll
            for (int oc4 = 0; oc4 < 4; ++oc4) {
                const float4 wv = *(const float4*)&w1s[k * 16 + oc4 * 4];
                const float wq[4] = {wv.x, wv.y, wv.z, wv.w};
                #pragma unroll
                for (int q = 0; q < 4; ++q) {
                    const int oc = oc4 * 4 + q;
                    a0[oc] += i0 * wq[q]; a1[oc] += i1 * wq[q]; a2[oc] += i2 * wq[q];
                }
            }
        }
        __syncthreads();
        #pragma unroll
        for (int i2_ = 0; i2_ < 8; ++i2_) {
            half2_t h0, h1;
            h0[0] = (half_t)fmaxf(a0[2 * i2_], 0.f); h0[1] = (half_t)fmaxf(a0[2 * i2_ + 1], 0.f);
            h1[0] = (half_t)fmaxf(a1[2 * i2_], 0.f); h1[1] = (half_t)fmaxf(a1[2 * i2_ + 1], 0.f);
            *(half2_t*)&plane1h[p0 * 16 + 2 * i2_] = h0;
            *(half2_t*)&plane1h[p1 * 16 + 2 * i2_] = h1;
        }
        if (v2) {
            #pragma unroll
            for (int i2_ = 0; i2_ < 8; ++i2_) {
                half2_t h2v;
                h2v[0] = (half_t)fmaxf(a2[2 * i2_], 0.f); h2v[1] = (half_t)fmaxf(a2[2 * i2_ + 1], 0.f);
                *(half2_t*)&plane1h[p2 * 16 + 2 * i2_] = h2v;
            }
        }
    }
    __syncthreads();

    // ---- conv2 (MFMA): 16->20(pad24), 25x25 -> 22x22, K=256 (8 steps) ----
    {
        half8_t B2f[8][2];
        const half8_t* Fv = (const half8_t*)F2;
        #pragma unroll
        for (int s = 0; s < 8; ++s) {
            B2f[s][0] = Fv[(s * 2 + 0) * 64 + l];
            B2f[s][1] = Fv[(s * 2 + 1) * 64 + l];
        }
        const float bias0 = b2[col];
        const float bias1 = (16 + col < 20) ? b2[16 + col] : 0.f;
        #pragma unroll 1
        for (int mt = wave; mt < 31; mt += 4) {
            const int pos = mt * 16 + col;
            const int py = pos / 22, px = pos - py * 22;
            const char* Ab = plane1b + (py * 25 + px) * 32 + g * 16;
            f32x4 c0 = {0.f, 0.f, 0.f, 0.f}, c1 = {0.f, 0.f, 0.f, 0.f};
            #pragma unroll
            for (int s = 0; s < 8; ++s) {
                const half8_t a = *(const half8_t*)(Ab + (s >> 1) * 800 + (s & 1) * 64);
                c0 = __builtin_amdgcn_mfma_f32_16x16x32_f16(a, B2f[s][0], c0, 0, 0, 0);
                c1 = __builtin_amdgcn_mfma_f32_16x16x32_f16(a, B2f[s][1], c1, 0, 0, 0);
            }
            #pragma unroll
            for (int r = 0; r < 4; ++r) {
                const int prow = mt * 16 + g * 4 + r;
                if (prow < 484) {
                    plane2h[prow * 24 + col] = (half_t)fmaxf(c0[r] + bias0, 0.f);
                    if (col < 8) {
                        const float v = (col < 4) ? fmaxf(c1[r] + bias1, 0.f) : 0.f;
                        plane2h[prow * 24 + 16 + col] = (half_t)v;
                    }
                }
            }
        }
    }
    __syncthreads();

    // ---- conv3 (MFMA): 24(in,pad)->24, 22x22 -> 19x19, K=384 (12 steps) ----
    {
        half8_t B3f[12][2];
        const half8_t* Fv = (const half8_t*)F3;
        #pragma unroll
        for (int s = 0; s < 12; ++s) {
            B3f[s][0] = Fv[(s * 2 + 0) * 64 + l];
            B3f[s][1] = Fv[(s * 2 + 1) * 64 + l];
        }
        const float bias0 = b3[col];
        const float bias1 = b3[16 + (col & 7)];
        #pragma unroll 1
        for (int mt = wave; mt < 23; mt += 4) {
            const int pos = mt * 16 + col;
            const int py = pos / 19, px = pos - py * 19;
            const char* Ab = plane2b + (py * 22 + px) * 48 + g * 16;
            f32x4 c0 = {0.f, 0.f, 0.f, 0.f}, c1 = {0.f, 0.f, 0.f, 0.f};
            #pragma unroll
            for (int s = 0; s < 12; ++s) {
                const half8_t a = *(const half8_t*)(Ab + (s / 3) * 1056 + (s % 3) * 64);
                c0 = __builtin_amdgcn_mfma_f32_16x16x32_f16(a, B3f[s][0], c0, 0, 0, 0);
                c1 = __builtin_amdgcn_mfma_f32_16x16x32_f16(a, B3f[s][1], c1, 0, 0, 0);
            }
            #pragma unroll
            for (int r = 0; r < 4; ++r) {
                const int prow = mt * 16 + g * 4 + r;
                if (prow < 361) {
                    plane3h[prow * 24 + col] = (half_t)fmaxf(c0[r] + bias0, 0.f);
                    if (col < 8)
                        plane3h[prow * 24 + 16 + col] = (half_t)fmaxf(c1[r] + bias1, 0.f);
                }
            }
        }
    }
    __syncthreads();

    // ---- conv4 (MFMA): 24->30, 19x19 -> 16x16; stage in LDS ----
    {
        half8_t B4f[12][2];
        const half8_t* Fv = (const half8_t*)F4;
        #pragma unroll
        for (int s = 0; s < 12; ++s) {
            B4f[s][0] = Fv[(s * 2 + 0) * 64 + l];
            B4f[s][1] = Fv[(s * 2 + 1) * 64 + l];
        }
        const float bias0 = b4[col];
        const float bias1 = (16 + col < 30) ? b4[16 + col] : 0.f;
        #pragma unroll 1
        for (int mt = wave; mt < 16; mt += 4) {
            const int pos = mt * 16 + col;
            const int py = pos >> 4, px = pos & 15;
            const char* Ab = plane1b + (py * 19 + px) * 48 + g * 16;   // plane3
            f32x4 c0 = {0.f, 0.f, 0.f, 0.f}, c1 = {0.f, 0.f, 0.f, 0.f};
            #pragma unroll
            for (int s = 0; s < 12; ++s) {
                const half8_t a = *(const half8_t*)(Ab + (s / 3) * 912 + (s % 3) * 64);
                c0 = __builtin_amdgcn_mfma_f32_16x16x32_f16(a, B4f[s][0], c0, 0, 0, 0);
                c1 = __builtin_amdgcn_mfma_f32_16x16x32_f16(a, B4f[s][1], c1, 0, 0, 0);
            }
            #pragma unroll
            for (int r = 0; r < 4; ++r) {
                const int prow = mt * 16 + g * 4 + r;   // < 256
                stage[prow * 32 + col] = (half_t)fmaxf(c0[r] + bias0, 0.f);
                if (col < 14)
                    stage[prow * 32 + 16 + col] = (half_t)fmaxf(c1[r] + bias1, 0.f);
            }
        }
        half2_t cc;
        cc[0] = (half_t)((float)(tid & 15) * 0.0625f);
        cc[1] = (half_t)((float)(tid >> 4) * 0.0625f);
        *(half2_t*)&stage[tid * 32 + 30] = cc;
    }
    __syncthreads();

    {
        const float4* sst  = (const float4*)stage;
        float4* gdst = (float4*)(hout + (size_t)b * 8192);
        #pragma unroll
        for (int k2 = 0; k2 < 4; ++k2)
            gdst[tid + 256 * k2] = sst[tid + 256 * k2];
    }
}

// ===========================================================================
__device__ __forceinline__ void block_reduce2(float& s1, float& s2, float* red)
{
    #pragma unroll
    for (int off = 32; off > 0; off >>= 1) {
        s1 += __shfl_down(s1, off);
        s2 += __shfl_down(s2, off);
    }
    const int lane = threadIdx.x & 63;
    const int wid  = threadIdx.x >> 6;
    if (lane == 0) { red[wid * 2] = s1; red[wid * 2 + 1] = s2; }
    __syncthreads();
    s1 = red[0] + red[2] + red[4] + red[6];
    s2 = red[1] + red[3] + red[5] + red[7];
    __syncthreads();
}

// Projection GEMM (bias in C-init) + scatter to [node][feat48] rows — the
// R8-verified pattern, factored (identical body).
__device__ __forceinline__ void proj_scatter(const half8_t hA[4],
                                             const float* __restrict__ W,
                                             const float* __restrict__ bias,
                                             half_t* scr, int w, int c, int g)
{
    half8_t Bf[3];
    #pragma unroll
    for (int nt = 0; nt < 3; ++nt) {
        const int row = 16 * nt + c;
        half8_t hb;
        if (row < 36) {
            const float4 w0 = *(const float4*)(W + row * 32 + 8 * g);
            const float4 w1 = *(const float4*)(W + row * 32 + 8 * g + 4);
            hb[0] = (half_t)w0.x; hb[1] = (half_t)w0.y; hb[2] = (half_t)w0.z; hb[3] = (half_t)w0.w;
            hb[4] = (half_t)w1.x; hb[5] = (half_t)w1.y; hb[6] = (half_t)w1.z; hb[7] = (half_t)w1.w;
        } else {
            #pragma unroll
            for (int j = 0; j < 8; ++j) hb[j] = (half_t)0.f;
        }
        Bf[nt] = hb;
    }
    f32x4 acc[4][3];
    #pragma unroll
    for (int nt = 0; nt < 3; ++nt) {
        const int o = 16 * nt + c;
        const float bv = (o < 36) ? bias[o] : 0.f;
        #pragma unroll
        for (int mt = 0; mt < 4; ++mt) acc[mt][nt] = (f32x4){bv, bv, bv, bv};
    }
    #pragma unroll
    for (int mt = 0; mt < 4; ++mt)
        #pragma unroll
        for (int nt = 0; nt < 3; ++nt)
            acc[mt][nt] = __builtin_amdgcn_mfma_f32_16x16x32_f16(hA[mt], Bf[nt], acc[mt][nt], 0, 0, 0);
    #pragma unroll
    for (int mt = 0; mt < 4; ++mt)
        #pragma unroll
        for (int nt = 0; nt < 3; ++nt)
            #pragma unroll
            for (int r = 0; r < 4; ++r)
                scr[(64 * w + 16 * mt + 4 * g + r) * 48 + 16 * nt + c] = (half_t)acc[mt][nt][r];
}

// Per-node joint LN: scalar row read (R8-verified), stats via block_reduce2,
// affine+scale into rowb[48] (36..47 zeroed).
__device__ __forceinline__ void ln_row(const half_t* buf, int tid,
                                       const float* __restrict__ gam,
                                       const float* __restrict__ bet,
                                       float scale, float* red, half_t* rowb)
{
    float rv[36];
    {
        const half_t* rp = buf + tid * 48;
        #pragma unroll
        for (int j = 0; j < 36; ++j) rv[j] = (float)rp[j];
    }
    float s1 = 0.f, s2 = 0.f;
    #pragma unroll
    for (int j = 0; j < 36; ++j) { s1 += rv[j]; s2 += rv[j] * rv[j]; }
    block_reduce2(s1, s2, red);
    const float mu  = s1 * (1.0f / 9216.0f);
    const float var = s2 * (1.0f / 9216.0f) - mu * mu;
    const float rs  = rsqrtf(var + LN_EPS);
    #pragma unroll
    for (int j4 = 0; j4 < 9; ++j4) {
        const float4 gm = *(const float4*)(gam + tid * 36 + 4 * j4);
        const float4 bt = *(const float4*)(bet + tid * 36 + 4 * j4);
        rowb[4*j4+0] = (half_t)(((rv[4*j4+0] - mu) * rs * gm.x + bt.x) * scale);
        rowb[4*j4+1] = (half_t)(((rv[4*j4+1] - mu) * rs * gm.y + bt.y) * scale);
        rowb[4*j4+2] = (half_t)(((rv[4*j4+2] - mu) * rs * gm.z + bt.z) * scale);
        rowb[4*j4+3] = (half_t)(((rv[4*j4+3] - mu) * rs * gm.w + bt.w) * scale);
    }
    #pragma unroll
    for (int j = 36; j < 48; ++j) rowb[j] = (half_t)0.f;
}

// ===========================================================================
// Attention + head, full-MFMA. Two time-shared 24KB buffers -> 3 blocks/CU:
//   BufA [256][48]: Q rows -> K rows -> att rows
//   BufB [256][48]: V raw -> Vt [48][256] swizzled -> l1 output rows
// l1: K=32 MFMA (proj-identical) + scalar tail for feats 32..35 (bisect of
// the K=16-MFMA suspect).
// ===========================================================================
__global__ __launch_bounds__(256, 3) void attn_head_kernel(
    const half_t* __restrict__ hbuf,
    const float* __restrict__ kW, const float* __restrict__ kb,
    const float* __restrict__ qW, const float* __restrict__ qb,
    const float* __restrict__ vW, const float* __restrict__ vb,
    const float* __restrict__ kg, const float* __restrict__ kbeta,
    const float* __restrict__ qg, const float* __restrict__ qbeta,
    const float* __restrict__ vg, const float* __restrict__ vbeta,
    const float* __restrict__ l1W, const float* __restrict__ l1b,
    const float* __restrict__ l2W, const float* __restrict__ l2b,
    float* __restrict__ out)
{
    __shared__ __attribute__((aligned(16))) char LDS[49152];
    __shared__ float red[8];
    __shared__ float epi[196];

    half_t* BufA = (half_t*)LDS;
    half_t* BufB = (half_t*)(LDS + 24576);
    half_t* Vt   = (half_t*)(LDS + 24576);

    const int b   = blockIdx.x;
    const int tid = threadIdx.x;
    const int w   = tid >> 6;
    const int l   = tid & 63;
    const int c   = l & 15;
    const int g   = l >> 4;

    // ---- h A-fragments (wave w owns node rows 64w..64w+63) ----
    half8_t hA[4];
    #pragma unroll
    for (int mt = 0; mt < 4; ++mt)
        hA[mt] = *(const half8_t*)(hbuf + ((size_t)b * 256 + 64 * w + 16 * mt + c) * 32 + 8 * g);

    // ---- Q -> BufA, V -> BufB (raw + bias) ----
    proj_scatter(hA, qW, qb, BufA, w, c, g);
    proj_scatter(hA, vW, vb, BufB, w, c, g);
    __syncthreads();                                   // S1: scatters visible

    // ---- Q LN (x 1/6), in-place own-row write ----
    {
        half_t rowb[48];
        ln_row(BufA, tid, qg, qbeta, (1.0f / 6.0f), red, rowb);
        #pragma unroll
        for (int i = 0; i < 6; ++i)
            *(half8_t*)(BufA + tid * 48 + 8 * i) = *(half8_t*)&rowb[8 * i];
    }
    // ---- V LN + in-place transpose into Vt ----
    {
        half_t rowb[48];
        ln_row(BufB, tid, vg, vbeta, 1.0f, red, rowb);
        #pragma unroll
        for (int j = 0; j < 48; ++j) {
            const half_t v = (j < 36) ? rowb[j] : (half_t)0.f;
            Vt[j * 256 + (tid ^ ((j & 7) << 2))] = v;
        }
    }
    __syncthreads();                                   // S2: Q rows + Vt visible

    // ---- Q fragments (wave-local rows) -> registers ----
    half8_t Qf32[4];
    half4_t Qf16[4];
    #pragma unroll
    for (int nt = 0; nt < 4; ++nt) {
        const int row = 64 * w + 16 * nt + c;
        Qf32[nt] = *(const half8_t*)(BufA + row * 48 + 8 * g);
        Qf16[nt] = *(const half4_t*)(BufA + row * 48 + 32 + 4 * g);
    }
    __syncthreads();                                   // S3: frag reads done, BufA free

    // ---- K -> BufA (raw), LN in place ----
    proj_scatter(hA, kW, kb, BufA, w, c, g);
    __syncthreads();                                   // S4
    {
        half_t rowb[48];
        ln_row(BufA, tid, kg, kbeta, 1.0f, red, rowb);
        #pragma unroll
        for (int i = 0; i < 6; ++i)
            *(half8_t*)(BufA + tid * 48 + 8 * i) = *(half8_t*)&rowb[8 * i];
    }
    __syncthreads();                                   // S5: K rows visible

    // ---- kv-loop: 8 chunks x 32 keys, no barriers ----
    float m[4], lsum[4];
    f32x4 att[3][4];
    #pragma unroll
    for (int nt = 0; nt < 4; ++nt) {
        m[nt] = -1e30f; lsum[nt] = 0.f;
        #pragma unroll
        for (int mt2 = 0; mt2 < 3; ++mt2) att[mt2][nt] = (f32x4){0.f, 0.f, 0.f, 0.f};
    }

    #pragma unroll 1
    for (int ch = 0; ch < 8; ++ch) {
        half8_t Ka32[2];
        half4_t Ka16[2];
        #pragma unroll
        for (int kt = 0; kt < 2; ++kt) {
            const int row = 32 * ch + 16 * kt + c;
            Ka32[kt] = *(const half8_t*)(BufA + row * 48 + 8 * g);
            Ka16[kt] = *(const half4_t*)(BufA + row * 48 + 32 + 4 * g);
        }
        half4_t Va[3][2];
        #pragma unroll
        for (int mt2 = 0; mt2 < 3; ++mt2)
            #pragma unroll
            for (int kc = 0; kc < 2; ++kc)
                Va[mt2][kc] = *(const half4_t*)(Vt + (16 * mt2 + c) * 256 +
                                ((32 * ch + 16 * kc + 4 * g) ^ ((c & 7) << 2)));

        // S^T chunk: rows = keys, cols = qrows
        f32x4 S[2][4];
        #pragma unroll
        for (int kt = 0; kt < 2; ++kt)
            #pragma unroll
            for (int nt = 0; nt < 4; ++nt) {
                f32x4 z = {0.f, 0.f, 0.f, 0.f};
                z = __builtin_amdgcn_mfma_f32_16x16x32_f16(Ka32[kt], Qf32[nt], z, 0, 0, 0);
                z = __builtin_amdgcn_mfma_f32_16x16x16f16(Ka16[kt], Qf16[nt], z, 0, 0, 0);
                S[kt][nt] = z;
            }

        // online softmax + PV per qrow-tile
        #pragma unroll
        for (int nt = 0; nt < 4; ++nt) {
            float cm = S[0][nt][0];
            cm = fmaxf(cm, S[0][nt][1]); cm = fmaxf(cm, S[0][nt][2]); cm = fmaxf(cm, S[0][nt][3]);
            cm = fmaxf(cm, S[1][nt][0]); cm = fmaxf(cm, S[1][nt][1]);
            cm = fmaxf(cm, S[1][nt][2]); cm = fmaxf(cm, S[1][nt][3]);
            cm = fmaxf(cm, __shfl_xor(cm, 16));
            cm = fmaxf(cm, __shfl_xor(cm, 32));
            const float newm  = fmaxf(m[nt], cm);
            const float alpha = __expf(m[nt] - newm);
            m[nt] = newm;
            lsum[nt] *= alpha;
            #pragma unroll
            for (int mt2 = 0; mt2 < 3; ++mt2) att[mt2][nt] *= alpha;

            half4_t P[2];
            #pragma unroll
            for (int kt = 0; kt < 2; ++kt) {
                const float p0 = __expf(S[kt][nt][0] - newm);
                const float p1 = __expf(S[kt][nt][1] - newm);
                const float p2 = __expf(S[kt][nt][2] - newm);
                const float p3 = __expf(S[kt][nt][3] - newm);
                lsum[nt] += (p0 + p1) + (p2 + p3);
                half4_t pp;
                pp[0] = (half_t)p0; pp[1] = (half_t)p1; pp[2] = (half_t)p2; pp[3] = (half_t)p3;
                P[kt] = pp;
            }
            #pragma unroll
            for (int mt2 = 0; mt2 < 3; ++mt2) {
                att[mt2][nt] = __builtin_amdgcn_mfma_f32_16x16x16f16(Va[mt2][0], P[0], att[mt2][nt], 0, 0, 0);
                att[mt2][nt] = __builtin_amdgcn_mfma_f32_16x16x16f16(Va[mt2][1], P[1], att[mt2][nt], 0, 0, 0);
            }
        }
    }
    __syncthreads();                                   // S6: kv reads of BufA/Vt done

    // ---- finalize att -> BufA rows (K dead) ----
    #pragma unroll
    for (int nt = 0; nt < 4; ++nt) {
        float lt = lsum[nt];
        lt += __shfl_xor(lt, 16);
        lt += __shfl_xor(lt, 32);
        const float inv = 1.0f / lt;
        const int row = 64 * w + 16 * nt + c;
        #pragma unroll
        for (int mt2 = 0; mt2 < 2; ++mt2)
            #pragma unroll
            for (int r = 0; r < 4; ++r)
                BufA[row * 48 + 16 * mt2 + 4 * g + r] = (half_t)(att[mt2][nt][r] * inv);
        if (g == 0) {
            #pragma unroll
            for (int r = 0; r < 4; ++r)
                BufA[row * 48 + 32 + r] = (half_t)(att[2][nt][r] * inv);
        }
    }
    __syncthreads();                                   // S7: att rows ready (feats 36..47 = 0 from K rows)

    // ---- l1: K=32 MFMA (proj-identical) + scalar tail feats 32..35 ----
    {
        half8_t La32[4];
        #pragma unroll
        for (int mt = 0; mt < 4; ++mt) {
            const int row = 64 * w + 16 * mt + c;
            La32[mt] = *(const half8_t*)(BufA + row * 48 + 8 * g);
        }
        // att tails for this lane's 16 C-rows (wave-broadcast reads)
        half4_t tail[4][4];
        #pragma unroll
        for (int mt = 0; mt < 4; ++mt)
            #pragma unroll
            for (int r = 0; r < 4; ++r) {
                const int crow = 64 * w + 16 * mt + 4 * g + r;
                tail[mt][r] = *(const half4_t*)(BufA + crow * 48 + 32);
            }
        f32x4 acc[4][3];
        #pragma unroll
        for (int nt = 0; nt < 3; ++nt) {
            const int jj = 16 * nt + c;
            const bool valid = jj < 36;
            half8_t hb32;
            float bv;
            if (valid) {
                const float4 w0 = *(const float4*)(l1W + jj * 36 + 8 * g);
                const float4 w1 = *(const float4*)(l1W + jj * 36 + 8 * g + 4);
                hb32[0] = (half_t)w0.x; hb32[1] = (half_t)w0.y; hb32[2] = (half_t)w0.z; hb32[3] = (half_t)w0.w;
                hb32[4] = (half_t)w1.x; hb32[5] = (half_t)w1.y; hb32[6] = (half_t)w1.z; hb32[7] = (half_t)w1.w;
                bv = l1b[jj];
            } else {
                #pragma unroll
                for (int j = 0; j < 8; ++j) hb32[j] = (half_t)0.f;
                bv = 0.f;
            }
            #pragma unroll
            for (int mt = 0; mt < 4; ++mt) {
                f32x4 ci = {bv, bv, bv, bv};
                acc[mt][nt] = __builtin_amdgcn_mfma_f32_16x16x32_f16(La32[mt], hb32, ci, 0, 0, 0);
            }
            // scalar tail: += sum_{d=32..35} att[crow][d] * l1W[jj][d]
            float tw0 = 0.f, tw1 = 0.f, tw2 = 0.f, tw3 = 0.f;
            if (valid) {
                const float4 wv = *(const float4*)(l1W + jj * 36 + 32);
                tw0 = wv.x; tw1 = wv.y; tw2 = wv.z; tw3 = wv.w;
            }
            #pragma unroll
            for (int mt = 0; mt < 4; ++mt)
                #pragma unroll
                for (int r = 0; r < 4; ++r)
                    acc[mt][nt][r] += (float)tail[mt][r][0] * tw0
                                    + (float)tail[mt][r][1] * tw1
                                    + (float)tail[mt][r][2] * tw2
                                    + (float)tail[mt][r][3] * tw3;
        }
        // ReLU + proj-identical scatter to BufB rows (Vt dead after S6)
        #pragma unroll
        for (int mt = 0; mt < 4; ++mt)
            #pragma unroll
            for (int nt = 0; nt < 3; ++nt)
                #pragma unroll
                for (int r = 0; r < 4; ++r)
                    BufB[(64 * w + 16 * mt + 4 * g + r) * 48 + 16 * nt + c] =
                        (half_t)fmaxf(acc[mt][nt][r], 0.f);
    }
    __syncthreads();                                   // S8: l1 rows ready

    // ---- epilogue (R10-verified): joint LN, butterfly max, head ----
    float a2[36];
    {
        const half_t* rp = BufB + tid * 48;
        #pragma unroll
        for (int j = 0; j < 36; ++j) a2[j] = (float)rp[j];
    }

    float s1 = 0.f, s2 = 0.f;
    #pragma unroll
    for (int j = 0; j < 36; ++j) { s1 += a2[j]; s2 += a2[j] * a2[j]; }
    block_reduce2(s1, s2, red);
    const float mu  = s1 * (1.0f / 9216.0f);
    const float rs  = rsqrtf(s2 * (1.0f / 9216.0f) - mu * mu + LN_EPS);

    float a3[36];
    #pragma unroll
    for (int j = 0; j < 36; ++j) a3[j] = (a2[j] - mu) * rs;

    // wave-level max butterfly over 64 nodes
    #pragma unroll
    for (int off = 1; off < 64; off <<= 1)
        #pragma unroll
        for (int j = 0; j < 36; ++j)
            a3[j] = fmaxf(a3[j], __shfl_xor(a3[j], off));
    if (l == 0) {
        #pragma unroll
        for (int j = 0; j < 36; ++j) epi[w * 36 + j] = a3[j];
    }
    __syncthreads();
    if (tid < 36)
        epi[144 + tid] = fmaxf(fmaxf(epi[tid], epi[36 + tid]),
                               fmaxf(epi[72 + tid], epi[108 + tid]));
    __syncthreads();
    if (tid < 10) {
        float y = l2b[tid];
        #pragma unroll
        for (int j = 0; j < 36; ++j) y += epi[144 + j] * l2W[tid * 36 + j];
        epi[180 + tid] = y;
    }
    __syncthreads();
    if (tid == 0) {
        float mx = epi[180];
        #pragma unroll
        for (int cc = 1; cc < 10; ++cc) mx = fmaxf(mx, epi[180 + cc]);
        float se = 0.f;
        #pragma unroll
        for (int cc = 0; cc < 10; ++cc) se += __expf(epi[180 + cc] - mx);
        const float lse = mx + logf(se);
        #pragma unroll
        for (int cc = 0; cc < 10; ++cc) out[b * 10 + cc] = epi[180 + cc] - lse;
    }
}

// ===========================================================================
extern "C" void kernel_launch(void* const* d_in, const int* in_sizes, int n_in,
                              void* d_out, int out_size, void* d_ws, size_t ws_size,
                              hipStream_t stream)
{
    const float* x     = (const float*)d_in[0];
    const float* w1    = (const float*)d_in[1];
    const float* b1    = (const float*)d_in[2];
    const float* w2    = (const float*)d_in[3];
    const float* b2    = (const float*)d_in[4];
    const float* w3    = (const float*)d_in[5];
    const float* b3    = (const float*)d_in[6];
    const float* w4    = (const float*)d_in[7];
    const float* b4    = (const float*)d_in[8];
    const float* kW    = (const float*)d_in[9];
    const float* kb    = (const float*)d_in[10];
    const float* qW    = (const float*)d_in[11];
    const float* qb    = (const float*)d_in[12];
    const float* vW    = (const float*)d_in[13];
    const float* vb    = (const float*)d_in[14];
    const float* kg    = (const float*)d_in[15];
    const float* kbeta = (const float*)d_in[16];
    const float* qg    = (const float*)d_in[17];
    const float* qbeta = (const float*)d_in[18];
    const float* vg    = (const float*)d_in[19];
    const float* vbeta = (const float*)d_in[20];
    const float* l1W   = (const float*)d_in[21];
    const float* l1b   = (const float*)d_in[22];
    const float* l2W   = (const float*)d_in[23];
    const float* l2b   = (const float*)d_in[24];

    const int B = in_sizes[0] / (28 * 28);            // 2048
    half_t* hbuf = (half_t*)d_ws;                     // [B,256,32] fp16 = 33.5 MB
    half_t* F2 = (half_t*)((char*)d_ws + 33554432);
    half_t* F3 = F2 + 8192;
    half_t* F4 = F3 + 12288;

    prep_weights_kernel<<<dim3(64), dim3(256), 0, stream>>>(w2, w3, w4, F2, F3, F4);
    conv_fused_kernel<<<dim3(B), dim3(256), 0, stream>>>(
        x, w1, b1, b2, b3, b4, F2, F3, F4, hbuf);
    attn_head_kernel<<<dim3(B), dim3(256), 0, stream>>>(
        hbuf, kW, kb, qW, qb, vW, vb,
        kg, kbeta, qg, qbeta, vg, vbeta,
        l1W, l1b, l2W, l2b, (float*)d_out);
}